// Round 4
// baseline (376.501 us; speedup 1.0000x reference)
//
#include <hip/hip_runtime.h>
#include <hip/hip_bf16.h>

// GCN 2-layer, N=100000, E=1.6M, 128->128->64.
// Round 14: XCD feature-slicing. h1/h2 stored in SLICED layout (slice = 16
// features, contiguous (N+1)x16 bf16 = 3.2MB < 4MB per-XCD L2). agg blocks
// with bid%8==s process only slice s -> all blocks of one slice land on one
// XCD (round-robin dispatch) -> gather working set is L2-RESIDENT. col/off2
// streams use nontemporal loads to avoid evicting the slice. FETCH floor
// drops 187MB -> ~100MB (agg1), ~50MB (agg2). Fusion undone (mini-GEMM needs
// full rows); gemm64 re-added reading/writing sliced layout.
// Also: bcur padded to 1 bucket per 64B line (k_part atomic storm: 570K
// device-scope RMWs previously concentrated on 49 lines).

#define IN_F  128
#define HID_F 128
#define OUT_F 64

#define NPB     128    // nodes per bucket (dst>>7)
#define MAXBKT  1024   // >= NBKT = ceil(N/128) = 782
#define CHUNK   2048   // edges per workgroup in hist/part
#define CAP     4096   // col staging capacity per bucket (mean ~2500 padded)
#define SLAB    4096   // slab edges per bucket

typedef __bf16 bf16_t;
typedef __bf16 bf16x4 __attribute__((ext_vector_type(4)));
typedef __bf16 bf16x8 __attribute__((ext_vector_type(8)));
typedef float  f32x2  __attribute__((ext_vector_type(2)));
typedef float  f32x4  __attribute__((ext_vector_type(4)));
typedef unsigned u32x2 __attribute__((ext_vector_type(2)));
typedef unsigned u32x4 __attribute__((ext_vector_type(4)));

// ---------------- pass A: bucket histogram + f2b + bcur init ----------------
__global__ __launch_bounds__(256) void k_hist(const int* __restrict__ dst, int E,
                                              int* __restrict__ chunkhist, int NBKT,
                                              int pchunks,
                                              const float* __restrict__ W1s,
                                              const float* __restrict__ W2s,
                                              bf16_t* __restrict__ Wdst,
                                              int n1, int n2,
                                              int* __restrict__ bcur) {
    if ((int)blockIdx.x >= pchunks) {
        int i = (blockIdx.x - pchunks) * 256 + threadIdx.x;
        if (i < n1) Wdst[i] = (bf16_t)W1s[i];
        else if (i < n1 + n2) Wdst[i] = (bf16_t)W2s[i - n1];
        else if (i < n1 + n2 + NBKT) bcur[(i - n1 - n2) * 16] = (i - n1 - n2) * SLAB;
        return;
    }
    __shared__ int cnt[MAXBKT];
    for (int i = threadIdx.x; i < NBKT; i += 256) cnt[i] = 0;
    __syncthreads();
    int base = blockIdx.x * CHUNK;
    for (int i = threadIdx.x; i < CHUNK; i += 256) {
        int e = base + i;
        if (e < E) atomicAdd(&cnt[dst[e] >> 7], 1);
    }
    __syncthreads();
    int* ch = chunkhist + (size_t)blockIdx.x * MAXBKT;
    for (int i = threadIdx.x; i < NBKT; i += 256) ch[i] = cnt[i];
}

// ---------------- pass B: partition edges into bucket slabs ----------------
// packed = (dst&127)<<17 | src  (src < 2^17 since N <= 131072)
// bcur strided 16 ints: one bucket per 64B line (atomic contention fix).
__global__ __launch_bounds__(256) void k_part(const int* __restrict__ src,
                                              const int* __restrict__ dst, int E,
                                              int* __restrict__ bcur,
                                              const int* __restrict__ chunkhist,
                                              unsigned* __restrict__ part, int NBKT) {
    __shared__ int cnt[MAXBKT];
    __shared__ int base[MAXBKT];
    const int* ch = chunkhist + (size_t)blockIdx.x * MAXBKT;
    int off = (int)((blockIdx.x * 331u) % (unsigned)NBKT);
    for (int j = threadIdx.x; j < NBKT; j += 256) {
        int i = j + off; if (i >= NBKT) i -= NBKT;
        int c = ch[i];
        base[i] = c ? atomicAdd(&bcur[i * 16], c) : 0;
        cnt[i] = 0;
    }
    __syncthreads();
    int cbase = blockIdx.x * CHUNK;
    for (int i = threadIdx.x; i < CHUNK; i += 256) {
        int e = cbase + i;
        if (e < E) {
            int d = dst[e];
            int b = d >> 7;
            int lp = atomicAdd(&cnt[b], 1);
            part[base[b] + lp] = (unsigned)src[e] | ((unsigned)(d & 127) << 17);
        }
    }
}

// ---------------- pass C: per-bucket CSR finalize (into col slab) ----------
// Edge lists padded to multiple of 8 with sentinel index N (zero row in h).
__global__ __launch_bounds__(256) void k_bucket(const unsigned* __restrict__ part,
                                                const int* __restrict__ bcur,
                                                int2* __restrict__ off2,
                                                int* __restrict__ col,
                                                float* __restrict__ dinv, int N) {
    __shared__ int lcnt[NPB];
    __shared__ int lexc[NPB];   // inclusive scan of PADDED counts
    __shared__ int lcur[NPB];
    __shared__ int stage[CAP];
    int b = blockIdx.x;
    int t = threadIdx.x;
    int node0 = b * NPB;
    int nb = min(NPB, N - node0);
    int e0s = b * SLAB;
    int cnt = bcur[b * 16] - e0s;
    if (t < NPB) lcnt[t] = 0;
    __syncthreads();
    for (int i = t; i < cnt; i += 256)
        atomicAdd(&lcnt[part[e0s + i] >> 17], 1);
    __syncthreads();
    if (t < NPB) lexc[t] = (lcnt[t] + 7) & ~7;
    __syncthreads();
    for (int ofs = 1; ofs < NPB; ofs <<= 1) {
        int add = (t >= ofs && t < NPB) ? lexc[t - ofs] : 0;
        __syncthreads();
        if (t < NPB) lexc[t] += add;
        __syncthreads();
    }
    if (t < NPB) {
        int pc = (lcnt[t] + 7) & ~7;
        int ex = lexc[t] - pc;
        lcur[t] = ex;
        if (t < nb) {
            off2[node0 + t] = make_int2(e0s + ex, e0s + ex + pc);
            dinv[node0 + t] = rsqrtf((float)lcnt[t] + 1.0f);
        }
    }
    __syncthreads();
    for (int i = t; i < cnt; i += 256) {
        unsigned p = part[e0s + i];
        int dl = p >> 17;
        int sv = (int)(p & 0x1FFFF);
        int lp = atomicAdd(&lcur[dl], 1);
        if (lp < CAP) stage[lp] = sv;
        else col[e0s + lp] = sv;  // statistically unreachable
    }
    __syncthreads();
    if (t < NPB) {
        int en = lexc[t];
        for (int i = lcur[t]; i < en; i++) {     // <= 7 pad slots per node
            if (i < CAP) stage[i] = N; else col[e0s + i] = N;
        }
    }
    __syncthreads();
    int tot = lexc[NPB - 1];
    for (int i = t; i < tot && i < CAP; i += 256) col[e0s + i] = stage[i];
}

// ---------------- MFMA GEMM + row-scale epilogue ----------------
// H[n,m] = scale[n] * sum_k X[n,k]*W[m,k], K=128.
// H stored SLICED: slice s (16 cols) at H + s*(N+1)*16, row-major within.
// Row N of H is written as zeros (gather sentinel for padded edge slots).
// IN_SLICED: X is bf16 in the same sliced layout (layer 2).
template <int NCOL, typename TIN, bool IN_SLICED>
__global__ __launch_bounds__(256) void k_gemm_mfma(const TIN* __restrict__ X,
                                                   const bf16_t* __restrict__ W,
                                                   const float* __restrict__ scale,
                                                   bf16_t* __restrict__ H, int N) {
    constexpr int CT = NCOL / 16;
    size_t sstride = (size_t)(N + 1) * 16;
    int wv = threadIdx.x >> 6, lane = threadIdx.x & 63;
    int quad = lane >> 4, l16 = lane & 15;
    int row0 = blockIdx.x * 128 + wv * 32;
    f32x4 acc[2][CT] = {};
#pragma unroll
    for (int ks = 0; ks < 4; ks++) {
        int k0 = ks * 32 + quad * 8;
        bf16x8 a[2];
#pragma unroll
        for (int rt = 0; rt < 2; rt++) {
            int r = row0 + rt * 16 + l16;
            if (r >= N) r = N - 1;
            if constexpr (IN_SLICED) {
                const bf16_t* p = (const bf16_t*)X + (size_t)(k0 >> 4) * sstride
                                  + (size_t)r * 16 + (k0 & 15);
                a[rt] = *(const bf16x8*)p;
            } else if constexpr (sizeof(TIN) == 4) {
                const TIN* p = X + (size_t)r * 128 + k0;
                f32x4 x0 = *(const f32x4*)p;
                f32x4 x1 = *(const f32x4*)(p + 4);
                bf16x8 tt;
                tt[0] = (bf16_t)x0[0]; tt[1] = (bf16_t)x0[1];
                tt[2] = (bf16_t)x0[2]; tt[3] = (bf16_t)x0[3];
                tt[4] = (bf16_t)x1[0]; tt[5] = (bf16_t)x1[1];
                tt[6] = (bf16_t)x1[2]; tt[7] = (bf16_t)x1[3];
                a[rt] = tt;
            } else {
                a[rt] = *(const bf16x8*)(X + (size_t)r * 128 + k0);
            }
        }
#pragma unroll
        for (int ct = 0; ct < CT; ct++) {
            bf16x8 bfrag = *(const bf16x8*)(W + (size_t)(ct * 16 + l16) * 128 + k0);
#pragma unroll
            for (int rt = 0; rt < 2; rt++)
                acc[rt][ct] = __builtin_amdgcn_mfma_f32_16x16x32_bf16(a[rt], bfrag, acc[rt][ct], 0, 0, 0);
        }
    }
#pragma unroll
    for (int rt = 0; rt < 2; rt++)
#pragma unroll
        for (int r4 = 0; r4 < 4; r4++) {
            int r = row0 + rt * 16 + quad * 4 + r4;
            if (r < N) {
                float sc = scale[r];
#pragma unroll
                for (int ct = 0; ct < CT; ct++)
                    H[(size_t)ct * sstride + (size_t)r * 16 + l16] = (bf16_t)(sc * acc[rt][ct][r4]);
            } else if (r == N) {
#pragma unroll
                for (int ct = 0; ct < CT; ct++)
                    H[(size_t)ct * sstride + (size_t)N * 16 + l16] = (bf16_t)0.f;
            }
        }
}

// ---------------- gather helpers (sliced: ROWE elems per row-slice) --------
template <int ROWE>
__device__ __forceinline__ void gather8(const bf16_t* __restrict__ hp,
                                        const int* __restrict__ col, int e,
                                        u32x4* w) {
    u32x4 c0 = __builtin_nontemporal_load((const u32x4*)(col + e));
    u32x4 c1 = __builtin_nontemporal_load((const u32x4*)(col + e + 4));
    w[0] = *(const u32x4*)(hp + (size_t)c0[0] * (unsigned)ROWE);
    w[1] = *(const u32x4*)(hp + (size_t)c0[1] * (unsigned)ROWE);
    w[2] = *(const u32x4*)(hp + (size_t)c0[2] * (unsigned)ROWE);
    w[3] = *(const u32x4*)(hp + (size_t)c0[3] * (unsigned)ROWE);
    w[4] = *(const u32x4*)(hp + (size_t)c1[0] * (unsigned)ROWE);
    w[5] = *(const u32x4*)(hp + (size_t)c1[1] * (unsigned)ROWE);
    w[6] = *(const u32x4*)(hp + (size_t)c1[2] * (unsigned)ROWE);
    w[7] = *(const u32x4*)(hp + (size_t)c1[3] * (unsigned)ROWE);
}

__device__ __forceinline__ void accum8(const u32x4* w, f32x2* a2) {
#pragma unroll
    for (int u = 0; u < 8; u++)
#pragma unroll
        for (int k = 0; k < 4; k++) {
            f32x2 v;
            v.x = __uint_as_float(w[u][k] << 16);
            v.y = __uint_as_float(w[u][k] & 0xffff0000u);
            a2[k] += v;                       // v_pk_add_f32
        }
}

// ---------------- sliced agg: slice = bid%8 class -> one XCD --------------
// NSL slices of 16 feats. 2 lanes/node (32B row-slice), 32 nodes/wave,
// 128 nodes/block. Gather source = this XCD's L2-resident slice.
// OUT_SLICED: write bf16 sliced layout; else fp32 row-major (NSL*16 cols).
template <int NSL, bool RELU, bool OUT_SLICED, typename TOUT>
__global__ __launch_bounds__(256) void k_agg_s(const bf16_t* __restrict__ h,
                                               const int2* __restrict__ off2,
                                               const int* __restrict__ col,
                                               const float* __restrict__ dinv,
                                               const float* __restrict__ bias,
                                               TOUT* __restrict__ out, int N) {
    constexpr int LANES8 = 8 / NSL;          // bid%8 classes per slice
    size_t sstride = (size_t)(N + 1) * 16;
    int r8 = blockIdx.x & 7;
    int slice = r8 / LANES8;
    int sub = r8 % LANES8;
    int chunk = blockIdx.x >> 3;
    int node0 = (chunk * LANES8 + sub) * 128;
    int lane = threadIdx.x & 63;
    int wv = threadIdx.x >> 6;
    int g = lane >> 1, fl = lane & 1;
    int node = node0 + wv * 32 + g;
    if (node >= N) return;
    int f = fl * 8;
    const bf16_t* hp = h + (size_t)slice * sstride + f;
    u32x4 ws = *(const u32x4*)(hp + (size_t)node * 16u);   // self row-slice
    int2 oe = off2[node];
    float di = dinv[node];
    f32x2 a2[4];
#pragma unroll
    for (int k = 0; k < 4; k++) {
        f32x2 v;
        v.x = __uint_as_float(ws[k] << 16);
        v.y = __uint_as_float(ws[k] & 0xffff0000u);
        a2[k] = v;
    }
    u32x4 w[8];
    for (int e = oe.x; e < oe.y; e += 8) {
        gather8<16>(hp, col, e, w);
        accum8(w, a2);
    }
    const float* bp = bias + slice * 16 + f;
    f32x4 b0 = *(const f32x4*)bp;
    f32x4 b1 = *(const f32x4*)(bp + 4);
    float r[8];
#pragma unroll
    for (int j = 0; j < 8; j++) {
        float bv = (j < 4) ? b0[j] : b1[j - 4];
        float val = a2[j >> 1][j & 1] * di + bv;
        if (RELU) val = fmaxf(val, 0.f);
        r[j] = val;
    }
    if constexpr (sizeof(TOUT) == 2) {
        bf16x8 v;
#pragma unroll
        for (int j = 0; j < 8; j++) v[j] = (bf16_t)r[j];
        __builtin_nontemporal_store(v, (bf16x8*)((bf16_t*)out + (size_t)slice * sstride + (size_t)node * 16 + f));
    } else {
        f32x4 v0 = {r[0], r[1], r[2], r[3]};
        f32x4 v1 = {r[4], r[5], r[6], r[7]};
        float* po = (float*)out + (size_t)node * (NSL * 16) + slice * 16 + f;
        __builtin_nontemporal_store(v0, (f32x4*)po);
        __builtin_nontemporal_store(v1, (f32x4*)(po + 4));
    }
}

extern "C" void kernel_launch(void* const* d_in, const int* in_sizes, int n_in,
                              void* d_out, int out_size, void* d_ws, size_t ws_size,
                              hipStream_t stream) {
    const float* x  = (const float*)d_in[0];
    const float* W1 = (const float*)d_in[1];
    const float* b1 = (const float*)d_in[2];
    const float* W2 = (const float*)d_in[3];
    const float* b2 = (const float*)d_in[4];
    const int*   ei = (const int*)d_in[5];

    int N = in_sizes[0] / IN_F;
    int E = in_sizes[5] / 2;
    const int* src = ei;
    const int* dst = ei + E;
    int NBKT = (N + NPB - 1) / NPB;           // 782
    int pchunks = (E + CHUNK - 1) / CHUNK;    // 782

    size_t woff = 0;
    auto alloc = [&](size_t bytes) {
        void* p = (char*)d_ws + woff;
        woff += (bytes + 255) & ~(size_t)255;
        return p;
    };
    int*      bcur  = (int*)alloc((size_t)NBKT * 16 * 4);   // 64B line per bucket
    int*      chist = (int*)alloc((size_t)pchunks * MAXBKT * 4);
    unsigned* part  = (unsigned*)alloc((size_t)NBKT * SLAB * 4);
    int*      col   = (int*)alloc((size_t)NBKT * SLAB * 4);
    int2*     off2  = (int2*)alloc((size_t)N * 8);
    float*    dinv  = (float*)alloc((size_t)N * 4);
    bf16_t*   Wb    = (bf16_t*)alloc((size_t)(HID_F * IN_F + OUT_F * HID_F) * 2);
    bf16_t*   W1b   = Wb;
    bf16_t*   W2b   = Wb + HID_F * IN_F;
    bf16_t*   h1    = (bf16_t*)alloc((size_t)(N + 1) * HID_F * 2);  // sliced, +zero row
    bf16_t*   h1r   = (bf16_t*)alloc((size_t)(N + 1) * HID_F * 2);  // sliced
    bf16_t*   h2b   = (bf16_t*)alloc((size_t)(N + 1) * OUT_F * 2);  // sliced, +zero row
    float*    outp  = (float*)d_out;

    int n1 = HID_F * IN_F, n2 = OUT_F * HID_F;
    int tailblocks = (n1 + n2 + NBKT + 255) / 256;
    k_hist<<<pchunks + tailblocks, 256, 0, stream>>>(dst, E, chist, NBKT, pchunks,
                                                     W1, W2, Wb, n1, n2, bcur);
    k_part<<<pchunks, 256, 0, stream>>>(src, dst, E, bcur, chist, part, NBKT);
    k_bucket<<<NBKT, 256, 0, stream>>>(part, bcur, off2, col, dinv, N);

    int CH = (N + 127) / 128;       // 782 node-chunks
    int gemm_blocks = CH;

    // layer 1: h1 = dinv * (x@W1^T)  [bf16 sliced, +zero row N]
    k_gemm_mfma<HID_F, float, false><<<gemm_blocks, 256, 0, stream>>>(x, W1b, dinv, h1, N);
    // agg1: slice s on XCD s (bid%8), gather L2-resident slice; relu -> h1r sliced
    k_agg_s<8, true, true, bf16_t><<<CH * 8, 256, 0, stream>>>(h1, off2, col, dinv, b1, h1r, N);
    // layer 2: h2 = dinv * (h1r@W2^T) [bf16 sliced, +zero row N]
    k_gemm_mfma<OUT_F, bf16_t, true><<<gemm_blocks, 256, 0, stream>>>(h1r, W2b, dinv, h2b, N);
    // agg2: 4 slices, 2 XCDs each; write fp32 row-major out
    k_agg_s<4, false, false, float><<<((CH + 1) / 2) * 8, 256, 0, stream>>>(h2b, off2, col, dinv, b2, outp, N);
}

// Round 5
// 266.179 us; speedup vs baseline: 1.4145x; 1.4145x over previous
//
#include <hip/hip_runtime.h>
#include <hip/hip_bf16.h>

// GCN 2-layer, N=100000, E=1.6M, 128->128->64.
// Round 15: revert agg/gemm to R13 (fused agg128+gemm64, row-major h, proven
// 62us agg). Attack setup passes:
//  - NPB 128->512 (196 buckets), CHUNK 2048->4096: k_part scatter runs go
//    ~10B -> ~84B (>= 1 line) => write amplification 5.7x -> ~1.5x; bcur
//    atomics 570K/49 lines -> 77K/196 padded lines.
//  - k_bucket redesigned for 512-node buckets (2 nodes/thread, 55KB LDS).
// R14's XCD slicing REVERTED: FETCH halved but txn count 8x'd => 2x slower
// (agg is transaction-bound at 256B-gather granularity, not byte-bound).

#define IN_F  128
#define HID_F 128
#define OUT_F 64

#define NPB     512    // nodes per bucket (dst>>9)
#define MAXBKT  256    // >= NBKT = ceil(N/512) = 196
#define CHUNK   4096   // edges per workgroup in hist/part
#define SLAB    12288  // slab edges per bucket (mean ~8.2K + ~1.8K pad)
#define CAP     12288  // col staging capacity per bucket (LDS)

typedef __bf16 bf16_t;
typedef __bf16 bf16x4 __attribute__((ext_vector_type(4)));
typedef __bf16 bf16x8 __attribute__((ext_vector_type(8)));
typedef float  f32x2  __attribute__((ext_vector_type(2)));
typedef float  f32x4  __attribute__((ext_vector_type(4)));
typedef unsigned u32x2 __attribute__((ext_vector_type(2)));
typedef unsigned u32x4 __attribute__((ext_vector_type(4)));

// ---------------- pass A: bucket histogram + f2b + bcur init ----------------
__global__ __launch_bounds__(256) void k_hist(const int* __restrict__ dst, int E,
                                              int* __restrict__ chunkhist, int NBKT,
                                              int pchunks,
                                              const float* __restrict__ W1s,
                                              const float* __restrict__ W2s,
                                              bf16_t* __restrict__ Wdst,
                                              int n1, int n2,
                                              int* __restrict__ bcur) {
    if ((int)blockIdx.x >= pchunks) {
        int i = (blockIdx.x - pchunks) * 256 + threadIdx.x;
        if (i < n1) Wdst[i] = (bf16_t)W1s[i];
        else if (i < n1 + n2) Wdst[i] = (bf16_t)W2s[i - n1];
        else if (i < n1 + n2 + NBKT) bcur[(i - n1 - n2) * 16] = (i - n1 - n2) * SLAB;
        return;
    }
    __shared__ int cnt[MAXBKT];
    for (int i = threadIdx.x; i < NBKT; i += 256) cnt[i] = 0;
    __syncthreads();
    int base = blockIdx.x * CHUNK;
    for (int i = threadIdx.x; i < CHUNK; i += 256) {
        int e = base + i;
        if (e < E) atomicAdd(&cnt[dst[e] >> 9], 1);
    }
    __syncthreads();
    int* ch = chunkhist + (size_t)blockIdx.x * MAXBKT;
    for (int i = threadIdx.x; i < NBKT; i += 256) ch[i] = cnt[i];
}

// ---------------- pass B: partition edges into bucket slabs ----------------
// packed = (dst&511)<<17 | src  (src < 2^17 since N <= 131072)
// bcur strided 16 ints (64B line per bucket). Rotated bucket loop spreads
// concurrent atomics across lines.
__global__ __launch_bounds__(256) void k_part(const int* __restrict__ src,
                                              const int* __restrict__ dst, int E,
                                              int* __restrict__ bcur,
                                              const int* __restrict__ chunkhist,
                                              unsigned* __restrict__ part, int NBKT) {
    __shared__ int cnt[MAXBKT];
    __shared__ int base[MAXBKT];
    const int* ch = chunkhist + (size_t)blockIdx.x * MAXBKT;
    int off = (int)((blockIdx.x * 73u) % (unsigned)NBKT);
    for (int j = threadIdx.x; j < NBKT; j += 256) {
        int i = j + off; if (i >= NBKT) i -= NBKT;
        int c = ch[i];
        base[i] = c ? atomicAdd(&bcur[i * 16], c) : 0;
        cnt[i] = 0;
    }
    __syncthreads();
    int cbase = blockIdx.x * CHUNK;
    for (int i = threadIdx.x; i < CHUNK; i += 256) {
        int e = cbase + i;
        if (e < E) {
            int d = dst[e];
            int b = d >> 9;
            int lp = atomicAdd(&cnt[b], 1);
            part[base[b] + lp] = (unsigned)src[e] | ((unsigned)(d & 511) << 17);
        }
    }
}

// ---------------- pass C: per-bucket CSR finalize (into col slab) ----------
// 512-node buckets, 2 nodes/thread. Edge lists padded to multiple of 8 with
// sentinel index N (zero row in h). col written coalesced from LDS stage.
__global__ __launch_bounds__(256) void k_bucket(const unsigned* __restrict__ part,
                                                const int* __restrict__ bcur,
                                                int2* __restrict__ off2,
                                                int* __restrict__ col,
                                                float* __restrict__ dinv, int N) {
    __shared__ int lcnt[NPB];     // 2 KB
    __shared__ int lexc[NPB];     // 2 KB  exclusive padded start per node
    __shared__ int lcur[NPB];     // 2 KB
    __shared__ int psum[256];     // 1 KB
    __shared__ int stage[CAP];    // 48 KB
    int b = blockIdx.x;
    int t = threadIdx.x;
    int node0 = b * NPB;
    int e0s = b * SLAB;
    int cnt = bcur[b * 16] - e0s;
    for (int i = t; i < NPB; i += 256) lcnt[i] = 0;
    __syncthreads();
    for (int i = t; i < cnt; i += 256)
        atomicAdd(&lcnt[part[e0s + i] >> 17], 1);
    __syncthreads();
    // two nodes per thread: sequential, then block-scan the 256 partials
    int n2b = t * 2;
    int pc0 = (lcnt[n2b] + 7) & ~7;
    int pc1 = (lcnt[n2b + 1] + 7) & ~7;
    psum[t] = pc0 + pc1;
    __syncthreads();
    for (int ofs = 1; ofs < 256; ofs <<= 1) {
        int add = (t >= ofs) ? psum[t - ofs] : 0;
        __syncthreads();
        psum[t] += add;
        __syncthreads();
    }
    int run = (t > 0) ? psum[t - 1] : 0;
    {
        lexc[n2b] = run; lcur[n2b] = run;
        int node = node0 + n2b;
        if (node < N) {
            off2[node] = make_int2(e0s + run, e0s + run + pc0);
            dinv[node] = rsqrtf((float)lcnt[n2b] + 1.0f);
        }
        run += pc0;
        lexc[n2b + 1] = run; lcur[n2b + 1] = run;
        node = node0 + n2b + 1;
        if (node < N) {
            off2[node] = make_int2(e0s + run, e0s + run + pc1);
            dinv[node] = rsqrtf((float)lcnt[n2b + 1] + 1.0f);
        }
    }
    __syncthreads();
    for (int i = t; i < cnt; i += 256) {
        unsigned p = part[e0s + i];
        int dl = p >> 17;
        int sv = (int)(p & 0x1FFFF);
        int lp = atomicAdd(&lcur[dl], 1);
        if (lp < CAP) stage[lp] = sv;
        else col[e0s + lp] = sv;  // statistically unreachable
    }
    __syncthreads();
#pragma unroll
    for (int j = 0; j < 2; j++) {
        int idx = n2b + j;
        int en = lexc[idx] + ((lcnt[idx] + 7) & ~7);
        for (int i = lcur[idx]; i < en; i++) {   // <= 7 pad slots per node
            if (i < CAP) stage[i] = N; else col[e0s + i] = N;
        }
    }
    __syncthreads();
    int tot = psum[255];
    for (int i = t; i < tot && i < CAP; i += 256) col[e0s + i] = stage[i];
}

// ---------------- MFMA GEMM + row-scale epilogue (layer 1) ----------------
// H[n,m] = scale[n] * sum_k X[n,k]*W[m,k], K=128, H stored bf16 row-major.
// Row N of H is written as zeros (gather sentinel for padded edge slots).
template <int NCOL, typename TIN>
__global__ __launch_bounds__(256) void k_gemm_mfma(const TIN* __restrict__ X,
                                                   const bf16_t* __restrict__ W,
                                                   const float* __restrict__ scale,
                                                   bf16_t* __restrict__ H, int N) {
    constexpr int CT = NCOL / 16;
    int wv = threadIdx.x >> 6, lane = threadIdx.x & 63;
    int quad = lane >> 4, l16 = lane & 15;
    int row0 = blockIdx.x * 128 + wv * 32;
    f32x4 acc[2][CT] = {};
#pragma unroll
    for (int ks = 0; ks < 4; ks++) {
        int k0 = ks * 32 + quad * 8;
        bf16x8 a[2];
#pragma unroll
        for (int rt = 0; rt < 2; rt++) {
            int r = row0 + rt * 16 + l16;
            if (r >= N) r = N - 1;
            const TIN* p = X + (size_t)r * 128 + k0;
            if constexpr (sizeof(TIN) == 4) {
                f32x4 x0 = *(const f32x4*)p;
                f32x4 x1 = *(const f32x4*)(p + 4);
                bf16x8 tt;
                tt[0] = (bf16_t)x0[0]; tt[1] = (bf16_t)x0[1];
                tt[2] = (bf16_t)x0[2]; tt[3] = (bf16_t)x0[3];
                tt[4] = (bf16_t)x1[0]; tt[5] = (bf16_t)x1[1];
                tt[6] = (bf16_t)x1[2]; tt[7] = (bf16_t)x1[3];
                a[rt] = tt;
            } else {
                a[rt] = *(const bf16x8*)p;
            }
        }
#pragma unroll
        for (int ct = 0; ct < CT; ct++) {
            bf16x8 bfrag = *(const bf16x8*)(W + (size_t)(ct * 16 + l16) * 128 + k0);
#pragma unroll
            for (int rt = 0; rt < 2; rt++)
                acc[rt][ct] = __builtin_amdgcn_mfma_f32_16x16x32_bf16(a[rt], bfrag, acc[rt][ct], 0, 0, 0);
        }
    }
#pragma unroll
    for (int rt = 0; rt < 2; rt++)
#pragma unroll
        for (int r4 = 0; r4 < 4; r4++) {
            int r = row0 + rt * 16 + quad * 4 + r4;
            if (r < N) {
                float sc = scale[r];
#pragma unroll
                for (int ct = 0; ct < CT; ct++)
                    H[(size_t)r * NCOL + ct * 16 + l16] = (bf16_t)(sc * acc[rt][ct][r4]);
            } else if (r == N) {
#pragma unroll
                for (int ct = 0; ct < CT; ct++)
                    H[(size_t)N * NCOL + ct * 16 + l16] = (bf16_t)0.f;
            }
        }
}

// ---------------- gather helpers ----------------
template <int ROWE>
__device__ __forceinline__ void gather8(const bf16_t* __restrict__ hp,
                                        const int* __restrict__ col, int e,
                                        u32x4* w) {
    int4 c0 = *(const int4*)(col + e);
    int4 c1 = *(const int4*)(col + e + 4);
    w[0] = *(const u32x4*)(hp + (unsigned)c0.x * (unsigned)ROWE);
    w[1] = *(const u32x4*)(hp + (unsigned)c0.y * (unsigned)ROWE);
    w[2] = *(const u32x4*)(hp + (unsigned)c0.z * (unsigned)ROWE);
    w[3] = *(const u32x4*)(hp + (unsigned)c0.w * (unsigned)ROWE);
    w[4] = *(const u32x4*)(hp + (unsigned)c1.x * (unsigned)ROWE);
    w[5] = *(const u32x4*)(hp + (unsigned)c1.y * (unsigned)ROWE);
    w[6] = *(const u32x4*)(hp + (unsigned)c1.z * (unsigned)ROWE);
    w[7] = *(const u32x4*)(hp + (unsigned)c1.w * (unsigned)ROWE);
}

__device__ __forceinline__ void accum8(const u32x4* w, f32x2* a2) {
#pragma unroll
    for (int u = 0; u < 8; u++)
#pragma unroll
        for (int k = 0; k < 4; k++) {
            f32x2 v;
            v.x = __uint_as_float(w[u][k] << 16);
            v.y = __uint_as_float(w[u][k] & 0xffff0000u);
            a2[k] += v;                       // v_pk_add_f32
        }
}

// ---------------- fused agg128 + gemm64 (layer-1 agg + layer-2 GEMM) -------
// 16 lanes/node, 4 nodes/wave, 16 nodes/block. Aggregate h1 + relu in regs,
// stage the 16x128 tile in LDS, then 4-wave MFMA 128->64 with dinv scale,
// writing h2 bf16 (+ zero row N). h1r never touches global memory.
__global__ __launch_bounds__(256) void k_agg_gemm(const bf16_t* __restrict__ h,
                                                  const int2* __restrict__ off2,
                                                  const int* __restrict__ col,
                                                  const float* __restrict__ dinv,
                                                  const float* __restrict__ bias,
                                                  const bf16_t* __restrict__ W2,
                                                  bf16_t* __restrict__ h2, int N) {
    __shared__ float hl[16][132];   // +4 pad: 2-way-max bank aliasing
    __shared__ float dl[16];
    int lane = threadIdx.x & 63;
    int wv = threadIdx.x >> 6;
    int g = lane >> 4, fl = lane & 15;
    int node0 = blockIdx.x * 16;
    int node = node0 + wv * 4 + g;
    bool alive = node < N;
    int f = fl * 8;
    const bf16_t* hp = h + f;
    f32x2 a2[4] = {};
    float di = 0.f;
    if (alive) {
        u32x4 ws = *(const u32x4*)(hp + (unsigned)node * 128u);   // self row
        int2 oe = off2[node];
        di = dinv[node];
#pragma unroll
        for (int k = 0; k < 4; k++) {
            f32x2 v;
            v.x = __uint_as_float(ws[k] << 16);
            v.y = __uint_as_float(ws[k] & 0xffff0000u);
            a2[k] = v;
        }
        u32x4 w[8];
        for (int e = oe.x; e < oe.y; e += 8) {
            gather8<128>(hp, col, e, w);
            accum8(w, a2);
        }
    }
    f32x4 b0 = *(const f32x4*)(bias + f);
    f32x4 b1 = *(const f32x4*)(bias + f + 4);
    int lr = wv * 4 + g;
#pragma unroll
    for (int j = 0; j < 8; j++) {
        float bv = (j < 4) ? b0[j] : b1[j - 4];
        float val = a2[j >> 1][j & 1] * di + bv;
        hl[lr][f + j] = fmaxf(val, 0.f);        // relu'd h1r row in LDS
    }
    if (fl == 0) dl[lr] = di;
    __syncthreads();

    // mini-GEMM: wave wv computes output cols [wv*16, wv*16+16)
    int quad = lane >> 4, l16 = lane & 15;
    f32x4 c4 = {0.f, 0.f, 0.f, 0.f};
#pragma unroll
    for (int ks = 0; ks < 4; ks++) {
        int k0 = ks * 32 + quad * 8;
        bf16x8 afr;
#pragma unroll
        for (int j = 0; j < 8; j++) afr[j] = (bf16_t)hl[l16][k0 + j];
        bf16x8 bfr = *(const bf16x8*)(W2 + (size_t)(wv * 16 + l16) * 128 + k0);
        c4 = __builtin_amdgcn_mfma_f32_16x16x32_bf16(afr, bfr, c4, 0, 0, 0);
    }
#pragma unroll
    for (int r4 = 0; r4 < 4; r4++) {
        int rr = quad * 4 + r4;
        int gn = node0 + rr;
        if (gn < N)
            h2[(size_t)gn * 64 + wv * 16 + l16] = (bf16_t)(dl[rr] * c4[r4]);
    }
    if (blockIdx.x == 0 && threadIdx.x < 32)    // zero sentinel row N of h2
        ((unsigned*)h2)[(size_t)N * 32 + threadIdx.x] = 0u;
}

// ---------------- agg, generic: LPN lanes/node, 64/LPN nodes/wave ---------
template <int ROWE, int LPN, bool RELU, typename TOUT>
__global__ __launch_bounds__(256) void k_agg(const bf16_t* __restrict__ h,
                                             const int2* __restrict__ off2,
                                             const int* __restrict__ col,
                                             const float* __restrict__ dinv,
                                             const float* __restrict__ bias,
                                             TOUT* __restrict__ out, int N) {
    constexpr int NPW = 64 / LPN;   // nodes per wave
    int lane = threadIdx.x & 63;
    int wv = threadIdx.x >> 6;
    int g = lane / LPN, fl = lane % LPN;
    int node = blockIdx.x * (4 * NPW) + wv * NPW + g;
    if (node >= N) return;
    int f = fl * 8;
    const bf16_t* hp = h + f;
    u32x4 ws = *(const u32x4*)(hp + (unsigned)node * (unsigned)ROWE); // self row
    int2 oe = off2[node];
    float di = dinv[node];
    f32x2 a2[4];
#pragma unroll
    for (int k = 0; k < 4; k++) {
        f32x2 v;
        v.x = __uint_as_float(ws[k] << 16);
        v.y = __uint_as_float(ws[k] & 0xffff0000u);
        a2[k] = v;
    }
    u32x4 w[8];
    for (int e = oe.x; e < oe.y; e += 8) {
        gather8<ROWE>(hp, col, e, w);
        accum8(w, a2);
    }
    f32x4 b0 = *(const f32x4*)(bias + f);
    f32x4 b1 = *(const f32x4*)(bias + f + 4);
    float r[8];
#pragma unroll
    for (int j = 0; j < 8; j++) {
        float bv = (j < 4) ? b0[j] : b1[j - 4];
        float val = a2[j >> 1][j & 1] * di + bv;
        if (RELU) val = fmaxf(val, 0.f);
        r[j] = val;
    }
    if constexpr (sizeof(TOUT) == 2) {
        bf16x8 v;
#pragma unroll
        for (int j = 0; j < 8; j++) v[j] = (bf16_t)r[j];
        *(bf16x8*)((bf16_t*)out + (size_t)node * ROWE + f) = v;
    } else {
        f32x4 v0 = {r[0], r[1], r[2], r[3]};
        f32x4 v1 = {r[4], r[5], r[6], r[7]};
        *(f32x4*)((float*)out + (size_t)node * ROWE + f) = v0;
        *(f32x4*)((float*)out + (size_t)node * ROWE + f + 4) = v1;
    }
}

extern "C" void kernel_launch(void* const* d_in, const int* in_sizes, int n_in,
                              void* d_out, int out_size, void* d_ws, size_t ws_size,
                              hipStream_t stream) {
    const float* x  = (const float*)d_in[0];
    const float* W1 = (const float*)d_in[1];
    const float* b1 = (const float*)d_in[2];
    const float* W2 = (const float*)d_in[3];
    const float* b2 = (const float*)d_in[4];
    const int*   ei = (const int*)d_in[5];

    int N = in_sizes[0] / IN_F;
    int E = in_sizes[5] / 2;
    const int* src = ei;
    const int* dst = ei + E;
    int NBKT = (N + NPB - 1) / NPB;           // 196
    int pchunks = (E + CHUNK - 1) / CHUNK;    // 391

    size_t woff = 0;
    auto alloc = [&](size_t bytes) {
        void* p = (char*)d_ws + woff;
        woff += (bytes + 255) & ~(size_t)255;
        return p;
    };
    int*      bcur  = (int*)alloc((size_t)NBKT * 16 * 4);   // 64B line per bucket
    int*      chist = (int*)alloc((size_t)pchunks * MAXBKT * 4);
    unsigned* part  = (unsigned*)alloc((size_t)NBKT * SLAB * 4);
    int*      col   = (int*)alloc((size_t)NBKT * SLAB * 4);
    int2*     off2  = (int2*)alloc((size_t)N * 8);
    float*    dinv  = (float*)alloc((size_t)N * 4);
    bf16_t*   Wb    = (bf16_t*)alloc((size_t)(HID_F * IN_F + OUT_F * HID_F) * 2);
    bf16_t*   W1b   = Wb;
    bf16_t*   W2b   = Wb + HID_F * IN_F;
    bf16_t*   h1    = (bf16_t*)alloc((size_t)(N + 1) * HID_F * 2);  // +1 zero row
    bf16_t*   h2b   = (bf16_t*)alloc((size_t)(N + 1) * OUT_F * 2);  // +1 zero row
    float*    outp  = (float*)d_out;

    int n1 = HID_F * IN_F, n2 = OUT_F * HID_F;
    int tailblocks = (n1 + n2 + NBKT + 255) / 256;
    k_hist<<<pchunks + tailblocks, 256, 0, stream>>>(dst, E, chist, NBKT, pchunks,
                                                     W1, W2, Wb, n1, n2, bcur);
    k_part<<<pchunks, 256, 0, stream>>>(src, dst, E, bcur, chist, part, NBKT);
    k_bucket<<<NBKT, 256, 0, stream>>>(part, bcur, off2, col, dinv, N);

    int gemm_blocks = (N + 127) / 128;

    // layer 1: h1 = dinv * (x@W1^T)  [bf16, +zero row N]
    k_gemm_mfma<HID_F, float><<<gemm_blocks, 256, 0, stream>>>(x, W1b, dinv, h1, N);
    // fused: agg(h1)+relu -> (in LDS) @ W2^T -> dinv-scale -> h2 [bf16]
    k_agg_gemm<<<(N + 15) / 16, 256, 0, stream>>>(h1, off2, col, dinv, b1, W2b, h2b, N);
    // layer 2 agg: gather h2 -> fp32 out
    k_agg<OUT_F, 8, false, float><<<(N + 31) / 32, 256, 0, stream>>>(h2b, off2, col, dinv, b2, outp, N);
}